// Round 22
// baseline (199.754 us; speedup 1.0000x reference)
//
#include <hip/hip_runtime.h>
#include <math.h>

// MS-SSIM loss, 5 levels, 11x11 separable Gaussian, zero padding.
// R22 = R21 level kernels (L0: 1-wave blocks, measured ~104us; L1-L4:
// 256-thread blocks, R19 verbatim) with the partial-sum array replaced by
// ONE device-scope atomicAdd(double) per block into acc[level] (R1's proven
// pattern; hipMemsetAsync zeroing is graph-safe). R21's 3072-entry partial
// array made the single-block combine kernel a ~48-iteration serial-latency
// loop; this removes it.

#define NIMG 48            // 16 * 3
#define TWO_C1 2.0e-4f     // 2 * (0.01*1.0)^2
#define TWO_C2 1.8e-3f     // 2 * (0.03*1.0)^2

typedef float f4v __attribute__((ext_vector_type(4), aligned(4)));
typedef float f2v __attribute__((ext_vector_type(2), aligned(4)));

#define FOR11(X) X(0) X(1) X(2) X(3) X(4) X(5) X(6) X(7) X(8) X(9) X(10)

#define TAPLOAD_M(K) \
  float p##K, t##K; { \
    const int x_ = gx + (K) - 5; \
    const int xc_ = min(max(x_, 0), W - 1); \
    const float pv_ = rp_[xc_], tv_ = rt_[xc_]; \
    const bool ok_ = ((unsigned)x_ < (unsigned)W); \
    p##K = ok_ ? pv_ : 0.f; t##K = ok_ ? tv_ : 0.f; }

#define HACC(K) { \
    hA_ = __builtin_fmaf(G##K, p##K, hA_); \
    hB_ = __builtin_fmaf(G##K, t##K, hB_); \
    const float u_ = __builtin_fmaf(t##K, t##K, p##K * p##K); \
    hP_ = __builtin_fmaf(G##K, u_, hP_); \
    const float x_ = p##K * t##K; \
    hQ_ = __builtin_fmaf(G##K, x_, hQ_); }

#define DECLR(K) float rA##K = 0.f, rB##K = 0.f, rP##K = 0.f, rQ##K = 0.f;

#define MS_STEP_N(R, SW) do { \
    const int r_ = (R); \
    float hA_ = 0.f, hB_ = 0.f, hP_ = 0.f, hQ_ = 0.f; \
    float pc_ = 0.f, tc_ = 0.f; \
    if ((unsigned)r_ < (unsigned)H) { \
      const float* rp_ = Pi + (size_t)r_ * W; \
      const float* rt_ = Ti + (size_t)r_ * W; \
      if (MASKED) { \
        FOR11(TAPLOAD_M) \
        FOR11(HACC) \
        pc_ = p5; tc_ = t5; \
      } else { \
        const float* rpl_ = rp_ + gx - 5; \
        const float* rtl_ = rt_ + gx - 5; \
        const f4v vpa_ = *(const f4v*)(rpl_); \
        const f4v vpb_ = *(const f4v*)(rpl_ + 4); \
        const f2v vpc_ = *(const f2v*)(rpl_ + 8); \
        const float p10 = rpl_[10]; \
        const f4v vta_ = *(const f4v*)(rtl_); \
        const f4v vtb_ = *(const f4v*)(rtl_ + 4); \
        const f2v vtc_ = *(const f2v*)(rtl_ + 8); \
        const float t10 = rtl_[10]; \
        const float p0 = vpa_.x, p1 = vpa_.y, p2 = vpa_.z, p3 = vpa_.w; \
        const float p4 = vpb_.x, p5 = vpb_.y, p6 = vpb_.z, p7 = vpb_.w; \
        const float p8 = vpc_.x, p9 = vpc_.y; \
        const float t0 = vta_.x, t1 = vta_.y, t2 = vta_.z, t3 = vta_.w; \
        const float t4 = vtb_.x, t5 = vtb_.y, t6 = vtb_.z, t7 = vtb_.w; \
        const float t8 = vtc_.x, t9 = vtc_.y; \
        FOR11(HACC) \
        pc_ = p5; tc_ = t5; \
      } \
    } \
    rA##SW = hA_; rB##SW = hB_; rP##SW = hP_; rQ##SW = hQ_; \
    if (DS) { \
      if (r_ >= y0 && r_ < y0 + nout) { \
        if ((r_ & 1) == 0) { pr = pc_; tr = tc_; } \
        else { \
          float sp_ = pr + pc_, st_ = tr + tc_; \
          sp_ += __shfl_xor(sp_, 1, 64); \
          st_ += __shfl_xor(st_, 1, 64); \
          if (((lane & 1) == 0) && (gx < W)) { \
            const size_t o_ = obase + (size_t)(r_ >> 1) * (size_t)(W >> 1) + \
                              (size_t)(gx >> 1); \
            dsP[o_] = sp_ * 0.25f; \
            dsT[o_] = st_ * 0.25f; \
          } } } } \
  } while (0)

#define VSTEP(GK, S) \
    A_ = __builtin_fmaf(GK, rA##S, A_); B_ = __builtin_fmaf(GK, rB##S, B_); \
    P_ = __builtin_fmaf(GK, rP##S, P_); Q_ = __builtin_fmaf(GK, rQ##S, Q_);

#define ROW_N(IROW, SW, S0,S1,S2,S3,S4,S5,S6,S7,S8,S9,S10) do { \
    const int i_ = (IROW); \
    const bool live_ = (i_ < nout); \
    MS_STEP_N(y0 + 5 + i_, SW); \
    float A_ = G0 * rA##S0, B_ = G0 * rB##S0; \
    float P_ = G0 * rP##S0, Q_ = G0 * rQ##S0; \
    VSTEP(G1, S1) VSTEP(G2, S2) VSTEP(G3, S3) VSTEP(G4, S4) VSTEP(G5, S5) \
    VSTEP(G6, S6) VSTEP(G7, S7) VSTEP(G8, S8) VSTEP(G9, S9) VSTEP(G10, S10) \
    const float m_ = A_ * B_; \
    const float q_ = __builtin_fmaf(A_, A_, B_ * B_); \
    const float cn_ = __builtin_fmaf(4.f, Q_ - m_, TWO_C2); \
    const float cd_ = __builtin_fmaf(2.f, P_ - q_, TWO_C2); \
    float val_; \
    if (LAST) { \
      const float ln_ = __builtin_fmaf(4.f, m_, TWO_C1); \
      const float ld_ = __builtin_fmaf(2.f, q_, TWO_C1); \
      val_ = (ln_ * cn_) / (ld_ * cd_); \
    } else { \
      val_ = cn_ / cd_; \
    } \
    if ((!MASKED || gx < W) && live_) sum += val_; \
  } while (0)

template <int MASKED, int DS, int LAST>
__device__ __forceinline__ float strip_run(
    const float* __restrict__ Pi, const float* __restrict__ Ti,
    const int H, const int W, const int y0, const int nout, const int c0,
    float* __restrict__ dsP, float* __restrict__ dsT, const size_t obase,
    const float G0, const float G1, const float G2, const float G3,
    const float G4, const float G5, const float G6, const float G7,
    const float G8, const float G9, const float G10) {
  const int lane = threadIdx.x & 63;
  const int gx = c0 + lane;
  FOR11(DECLR)
  float pr = 0.f, tr = 0.f, sum = 0.f;

  MS_STEP_N(y0 - 5, 0); MS_STEP_N(y0 - 4, 1); MS_STEP_N(y0 - 3, 2);
  MS_STEP_N(y0 - 2, 3); MS_STEP_N(y0 - 1, 4); MS_STEP_N(y0 + 0, 5);
  MS_STEP_N(y0 + 1, 6); MS_STEP_N(y0 + 2, 7); MS_STEP_N(y0 + 3, 8);
  MS_STEP_N(y0 + 4, 9);

  for (int base = 0; base < nout; base += 11) {
    ROW_N(base + 0, 10, 0,1,2,3,4,5,6,7,8,9,10);
    ROW_N(base + 1, 0,  1,2,3,4,5,6,7,8,9,10,0);
    ROW_N(base + 2, 1,  2,3,4,5,6,7,8,9,10,0,1);
    ROW_N(base + 3, 2,  3,4,5,6,7,8,9,10,0,1,2);
    ROW_N(base + 4, 3,  4,5,6,7,8,9,10,0,1,2,3);
    ROW_N(base + 5, 4,  5,6,7,8,9,10,0,1,2,3,4);
    ROW_N(base + 6, 5,  6,7,8,9,10,0,1,2,3,4,5);
    ROW_N(base + 7, 6,  7,8,9,10,0,1,2,3,4,5,6);
    ROW_N(base + 8, 7,  8,9,10,0,1,2,3,4,5,6,7);
    ROW_N(base + 9, 8,  9,10,0,1,2,3,4,5,6,7,8);
    ROW_N(base + 10, 9, 10,0,1,2,3,4,5,6,7,8,9);
  }
  return sum;
}

// ---- L0 wrapper: 1-wave workgroups, one atomicAdd per block ----
template <int DS, int LAST>
__global__ __launch_bounds__(64)
void msssim_level64_k(const float* __restrict__ P, const float* __restrict__ T,
                      const int H, const int W, const int strips,
                      const int chunks, const int chunkH,
                      float* __restrict__ dsP, float* __restrict__ dsT,
                      double* __restrict__ acc,
                      const float G0, const float G1, const float G2,
                      const float G3, const float G4, const float G5,
                      const float G6, const float G7, const float G8,
                      const float G9, const float G10) {
  const int lane = threadIdx.x & 63;
  const int task = blockIdx.x;
  const int strip = task % strips;
  const int rem = task / strips;
  const int chunk = rem % chunks;
  const int img = rem / chunks;
  const int y0 = chunk * chunkH;
  const int nout = min(chunkH, H - y0);
  const size_t ibase = (size_t)img * H * W;
  const size_t obase = DS ? (size_t)img * (size_t)(H >> 1) * (W >> 1) : 0;
  const bool edge = (strip == 0) || (strip * 64 + 69 > W);
  float sum;
  if (edge)
    sum = strip_run<1, DS, LAST>(P + ibase, T + ibase, H, W, y0, nout,
                                 strip * 64, dsP, dsT, obase,
                                 G0, G1, G2, G3, G4, G5, G6, G7, G8, G9, G10);
  else
    sum = strip_run<0, DS, LAST>(P + ibase, T + ibase, H, W, y0, nout,
                                 strip * 64, dsP, dsT, obase,
                                 G0, G1, G2, G3, G4, G5, G6, G7, G8, G9, G10);
#pragma unroll
  for (int off = 32; off; off >>= 1) sum += __shfl_down(sum, off, 64);
  if (lane == 0) atomicAdd(acc, (double)sum);
}

// ---- L1-L4 wrapper: 256-thread workgroups, one atomicAdd per block ----
template <int DS, int LAST>
__global__ __launch_bounds__(256)
void msssim_level_k(const float* __restrict__ P, const float* __restrict__ T,
                    const int H, const int W, const int strips,
                    const int chunks, const int chunkH, const int tasks,
                    float* __restrict__ dsP, float* __restrict__ dsT,
                    double* __restrict__ acc,
                    const float G0, const float G1, const float G2,
                    const float G3, const float G4, const float G5,
                    const float G6, const float G7, const float G8,
                    const float G9, const float G10) {
  __shared__ float sRed[4];
  const int tid = threadIdx.x;
  const int lane = tid & 63;
  const int wid = tid >> 6;
  float sum = 0.f;
  const int task = blockIdx.x * 4 + wid;
  if (task < tasks) {
    const int strip = task % strips;
    const int rem = task / strips;
    const int chunk = rem % chunks;
    const int img = rem / chunks;
    const int y0 = chunk * chunkH;
    const int nout = min(chunkH, H - y0);
    const size_t ibase = (size_t)img * H * W;
    const size_t obase = DS ? (size_t)img * (size_t)(H >> 1) * (W >> 1) : 0;
    const bool edge = (strip == 0) || (strip * 64 + 69 > W);
    if (edge)
      sum = strip_run<1, DS, LAST>(P + ibase, T + ibase, H, W, y0, nout,
                                   strip * 64, dsP, dsT, obase,
                                   G0, G1, G2, G3, G4, G5, G6, G7, G8, G9, G10);
    else
      sum = strip_run<0, DS, LAST>(P + ibase, T + ibase, H, W, y0, nout,
                                   strip * 64, dsP, dsT, obase,
                                   G0, G1, G2, G3, G4, G5, G6, G7, G8, G9, G10);
  }
#pragma unroll
  for (int off = 32; off; off >>= 1) sum += __shfl_down(sum, off, 64);
  if (lane == 0) sRed[wid] = sum;
  __syncthreads();
  if (tid == 0)
    atomicAdd(acc, (double)(sRed[0] + sRed[1] + sRed[2] + sRed[3]));
}

__global__ void msssim_combine_k(const double* __restrict__ acc,
                                 float* __restrict__ out) {
  double ms = acc[4] / (48.0 * 32.0 * 32.0);
  ms *= pow(acc[0] / (48.0 * 512.0 * 512.0), (double)0.0448f);
  ms *= pow(acc[1] / (48.0 * 256.0 * 256.0), (double)0.2856f);
  ms *= pow(acc[2] / (48.0 * 128.0 * 128.0), (double)0.3001f);
  ms *= pow(acc[3] / (48.0 * 64.0 * 64.0),  (double)0.2363f);
  out[0] = (float)(1.0 - ms);
}

extern "C" void kernel_launch(void* const* d_in, const int* in_sizes, int n_in,
                              void* d_out, int out_size, void* d_ws, size_t ws_size,
                              hipStream_t stream) {
  const float* pred = (const float*)d_in[0];
  const float* targ = (const float*)d_in[1];
  float* out = (float*)d_out;

  char* ws = (char*)d_ws;
  double* acc = (double*)ws;   // 5 level accumulators
  size_t off = 256;
  auto alloc = [&](size_t elems) {
    float* p = (float*)(ws + off);
    off += elems * sizeof(float);
    return p;
  };
  float* L1p = alloc((size_t)NIMG * 256 * 256);
  float* L1t = alloc((size_t)NIMG * 256 * 256);
  float* L2p = alloc((size_t)NIMG * 128 * 128);
  float* L2t = alloc((size_t)NIMG * 128 * 128);
  float* L3p = alloc((size_t)NIMG * 64 * 64);
  float* L3t = alloc((size_t)NIMG * 64 * 64);
  float* L4p = alloc((size_t)NIMG * 32 * 32);
  float* L4t = alloc((size_t)NIMG * 32 * 32);

  hipMemsetAsync(acc, 0, 5 * sizeof(double), stream);

  float g[11];
  {
    double gd[11], s = 0.0;
    for (int k = 0; k < 11; ++k) {
      const double c = (double)(k - 5);
      gd[k] = exp(-(c * c) / 4.5);  // 2*sigma^2 = 4.5
      s += gd[k];
    }
    for (int k = 0; k < 11; ++k) g[k] = (float)(gd[k] / s);
  }

  // L0: 1-wave blocks, CH=64.
  {
    const int strips = 8, chunks = 8;
    const int tasks = strips * chunks * NIMG;  // 3072 blocks
    msssim_level64_k<1, 0><<<tasks, 64, 0, stream>>>(
        pred, targ, 512, 512, strips, chunks, 64, L1p, L1t, acc + 0,
        g[0], g[1], g[2], g[3], g[4], g[5], g[6], g[7], g[8], g[9], g[10]);
  }

  auto launchLevel = [&](const float* P, const float* T, int H, int W,
                         int chunkH, float* dP, float* dT, int L, bool last) {
    const int strips = (W + 63) / 64;
    const int chunks = (H + chunkH - 1) / chunkH;
    const int tasks = strips * chunks * NIMG;
    const int blocks = (tasks + 3) / 4;
    if (last) {
      msssim_level_k<0, 1><<<blocks, 256, 0, stream>>>(
          P, T, H, W, strips, chunks, chunkH, tasks, nullptr, nullptr,
          acc + L, g[0], g[1], g[2], g[3], g[4], g[5], g[6], g[7], g[8],
          g[9], g[10]);
    } else {
      msssim_level_k<1, 0><<<blocks, 256, 0, stream>>>(
          P, T, H, W, strips, chunks, chunkH, tasks, dP, dT,
          acc + L, g[0], g[1], g[2], g[3], g[4], g[5], g[6], g[7], g[8],
          g[9], g[10]);
    }
  };

  launchLevel(L1p, L1t, 256, 256, 16, L2p, L2t, 1, false);
  launchLevel(L2p, L2t, 128, 128, 8, L3p, L3t, 2, false);
  launchLevel(L3p, L3t, 64, 64, 8, L4p, L4t, 3, false);
  launchLevel(L4p, L4t, 32, 32, 8, nullptr, nullptr, 4, true);

  msssim_combine_k<<<1, 1, 0, stream>>>(acc, out);
}

// Round 23
// 176.920 us; speedup vs baseline: 1.1291x; 1.1291x over previous
//
#include <hip/hip_runtime.h>
#include <math.h>

// MS-SSIM loss, 5 levels, 11x11 separable Gaussian, zero padding.
// R23 = R19 byte-exact (the verified best: 178.2us). R20-R22 tested 1-wave
// L0 blocks and atomic reductions; all landed 193-207us (the apparent
// "1-wave L0 win" was run noise: 103/104/121us across three rounds).
// Final operating point: named-scalar ring, branch-local taps, vectorized
// interior loads, (p,t,p^2+t^2,pt) basis, plain __launch_bounds__(256),
// L0 CH=64 / L1 CH=16 / L2-L4 CH=8, partial-array + 64-lane combine.
// VGPR=64, zero scratch, VALUBusy ~52%, HBM ~11% -- latency-bound TLP
// optimum; all ILP/occupancy/block-size/reduction levers measured worse.

#define NIMG 48            // 16 * 3
#define TWO_C1 2.0e-4f     // 2 * (0.01*1.0)^2
#define TWO_C2 1.8e-3f     // 2 * (0.03*1.0)^2

struct CInfo { int base[5]; int cnt[5]; };

typedef float f4v __attribute__((ext_vector_type(4), aligned(4)));
typedef float f2v __attribute__((ext_vector_type(2), aligned(4)));

#define FOR11(X) X(0) X(1) X(2) X(3) X(4) X(5) X(6) X(7) X(8) X(9) X(10)

// --- masked tap loads (edge strips) ---
#define TAPLOAD_M(K) \
  float p##K, t##K; { \
    const int x_ = gx + (K) - 5; \
    const int xc_ = min(max(x_, 0), W - 1); \
    const float pv_ = rp_[xc_], tv_ = rt_[xc_]; \
    const bool ok_ = ((unsigned)x_ < (unsigned)W); \
    p##K = ok_ ? pv_ : 0.f; t##K = ok_ ? tv_ : 0.f; }

// --- horizontal accumulate: fields (p, t, p^2+t^2, p*t), 7 ops/tap ---
#define HACC(K) { \
    hA_ = __builtin_fmaf(G##K, p##K, hA_); \
    hB_ = __builtin_fmaf(G##K, t##K, hB_); \
    const float u_ = __builtin_fmaf(t##K, t##K, p##K * p##K); \
    hP_ = __builtin_fmaf(G##K, u_, hP_); \
    const float x_ = p##K * t##K; \
    hQ_ = __builtin_fmaf(G##K, x_, hQ_); }

// --- ring scalar declarations ---
#define DECLR(K) float rA##K = 0.f, rB##K = 0.f, rP##K = 0.f, rQ##K = 0.f;

// One input row R: load taps, horizontal conv into ring slot SW (literal),
// fused 2x2 avg-pool on center taps. Interior path: 8 vector loads.
#define MS_STEP_N(R, SW) do { \
    const int r_ = (R); \
    float hA_ = 0.f, hB_ = 0.f, hP_ = 0.f, hQ_ = 0.f; \
    float pc_ = 0.f, tc_ = 0.f; \
    if ((unsigned)r_ < (unsigned)H) { \
      const float* rp_ = Pi + (size_t)r_ * W; \
      const float* rt_ = Ti + (size_t)r_ * W; \
      if (MASKED) { \
        FOR11(TAPLOAD_M) \
        FOR11(HACC) \
        pc_ = p5; tc_ = t5; \
      } else { \
        const float* rpl_ = rp_ + gx - 5; \
        const float* rtl_ = rt_ + gx - 5; \
        const f4v vpa_ = *(const f4v*)(rpl_); \
        const f4v vpb_ = *(const f4v*)(rpl_ + 4); \
        const f2v vpc_ = *(const f2v*)(rpl_ + 8); \
        const float p10 = rpl_[10]; \
        const f4v vta_ = *(const f4v*)(rtl_); \
        const f4v vtb_ = *(const f4v*)(rtl_ + 4); \
        const f2v vtc_ = *(const f2v*)(rtl_ + 8); \
        const float t10 = rtl_[10]; \
        const float p0 = vpa_.x, p1 = vpa_.y, p2 = vpa_.z, p3 = vpa_.w; \
        const float p4 = vpb_.x, p5 = vpb_.y, p6 = vpb_.z, p7 = vpb_.w; \
        const float p8 = vpc_.x, p9 = vpc_.y; \
        const float t0 = vta_.x, t1 = vta_.y, t2 = vta_.z, t3 = vta_.w; \
        const float t4 = vtb_.x, t5 = vtb_.y, t6 = vtb_.z, t7 = vtb_.w; \
        const float t8 = vtc_.x, t9 = vtc_.y; \
        FOR11(HACC) \
        pc_ = p5; tc_ = t5; \
      } \
    } \
    rA##SW = hA_; rB##SW = hB_; rP##SW = hP_; rQ##SW = hQ_; \
    if (DS) { \
      if (r_ >= y0 && r_ < y0 + nout) { \
        if ((r_ & 1) == 0) { pr = pc_; tr = tc_; } \
        else { \
          float sp_ = pr + pc_, st_ = tr + tc_; \
          sp_ += __shfl_xor(sp_, 1, 64); \
          st_ += __shfl_xor(st_, 1, 64); \
          if (((lane & 1) == 0) && (gx < W)) { \
            const size_t o_ = obase + (size_t)(r_ >> 1) * (size_t)(W >> 1) + \
                              (size_t)(gx >> 1); \
            dsP[o_] = sp_ * 0.25f; \
            dsT[o_] = st_ * 0.25f; \
          } } } } \
  } while (0)

#define VSTEP(GK, S) \
    A_ = __builtin_fmaf(GK, rA##S, A_); B_ = __builtin_fmaf(GK, rB##S, B_); \
    P_ = __builtin_fmaf(GK, rP##S, P_); Q_ = __builtin_fmaf(GK, rQ##S, Q_);

// One output row. SW/S0..S10 are literal slot numbers; S_k holds row (i-5+k).
// After v-conv: A_=mu_p, B_=mu_t, P_=E[p^2+t^2], Q_=E[pt].
#define ROW_N(IROW, SW, S0,S1,S2,S3,S4,S5,S6,S7,S8,S9,S10) do { \
    const int i_ = (IROW); \
    const bool live_ = (i_ < nout); \
    MS_STEP_N(y0 + 5 + i_, SW); \
    float A_ = G0 * rA##S0, B_ = G0 * rB##S0; \
    float P_ = G0 * rP##S0, Q_ = G0 * rQ##S0; \
    VSTEP(G1, S1) VSTEP(G2, S2) VSTEP(G3, S3) VSTEP(G4, S4) VSTEP(G5, S5) \
    VSTEP(G6, S6) VSTEP(G7, S7) VSTEP(G8, S8) VSTEP(G9, S9) VSTEP(G10, S10) \
    const float m_ = A_ * B_; \
    const float q_ = __builtin_fmaf(A_, A_, B_ * B_); \
    const float cn_ = __builtin_fmaf(4.f, Q_ - m_, TWO_C2); \
    const float cd_ = __builtin_fmaf(2.f, P_ - q_, TWO_C2); \
    float val_; \
    if (LAST) { \
      const float ln_ = __builtin_fmaf(4.f, m_, TWO_C1); \
      const float ld_ = __builtin_fmaf(2.f, q_, TWO_C1); \
      val_ = (ln_ * cn_) / (ld_ * cd_); \
    } else { \
      val_ = cn_ / cd_; \
    } \
    if ((!MASKED || gx < W) && live_) sum += val_; \
  } while (0)

template <int MASKED, int DS, int LAST>
__device__ __forceinline__ float strip_run(
    const float* __restrict__ Pi, const float* __restrict__ Ti,
    const int H, const int W, const int y0, const int nout, const int c0,
    float* __restrict__ dsP, float* __restrict__ dsT, const size_t obase,
    const float G0, const float G1, const float G2, const float G3,
    const float G4, const float G5, const float G6, const float G7,
    const float G8, const float G9, const float G10) {
  const int lane = threadIdx.x & 63;
  const int gx = c0 + lane;
  FOR11(DECLR)                       // rA0..rQ10, all named scalars
  float pr = 0.f, tr = 0.f, sum = 0.f;

  // Prologue: slots 0..9 <- rows y0-5 .. y0+4.
  MS_STEP_N(y0 - 5, 0); MS_STEP_N(y0 - 4, 1); MS_STEP_N(y0 - 3, 2);
  MS_STEP_N(y0 - 2, 3); MS_STEP_N(y0 - 1, 4); MS_STEP_N(y0 + 0, 5);
  MS_STEP_N(y0 + 1, 6); MS_STEP_N(y0 + 2, 7); MS_STEP_N(y0 + 3, 8);
  MS_STEP_N(y0 + 4, 9);

  // Main: 11 phases per iteration; slot lists rotate by one each phase.
  for (int base = 0; base < nout; base += 11) {
    ROW_N(base + 0, 10, 0,1,2,3,4,5,6,7,8,9,10);
    ROW_N(base + 1, 0,  1,2,3,4,5,6,7,8,9,10,0);
    ROW_N(base + 2, 1,  2,3,4,5,6,7,8,9,10,0,1);
    ROW_N(base + 3, 2,  3,4,5,6,7,8,9,10,0,1,2);
    ROW_N(base + 4, 3,  4,5,6,7,8,9,10,0,1,2,3);
    ROW_N(base + 5, 4,  5,6,7,8,9,10,0,1,2,3,4);
    ROW_N(base + 6, 5,  6,7,8,9,10,0,1,2,3,4,5);
    ROW_N(base + 7, 6,  7,8,9,10,0,1,2,3,4,5,6);
    ROW_N(base + 8, 7,  8,9,10,0,1,2,3,4,5,6,7);
    ROW_N(base + 9, 8,  9,10,0,1,2,3,4,5,6,7,8);
    ROW_N(base + 10, 9, 10,0,1,2,3,4,5,6,7,8,9);
  }
  return sum;
}

template <int DS, int LAST>
__global__ __launch_bounds__(256)
void msssim_level_k(const float* __restrict__ P, const float* __restrict__ T,
                    const int H, const int W, const int strips,
                    const int chunks, const int chunkH, const int tasks,
                    float* __restrict__ dsP, float* __restrict__ dsT,
                    double* __restrict__ partial,
                    const float G0, const float G1, const float G2,
                    const float G3, const float G4, const float G5,
                    const float G6, const float G7, const float G8,
                    const float G9, const float G10) {
  __shared__ float sRed[4];
  const int tid = threadIdx.x;
  const int lane = tid & 63;
  const int wid = tid >> 6;
  float sum = 0.f;
  const int task = blockIdx.x * 4 + wid;
  if (task < tasks) {
    const int strip = task % strips;
    const int rem = task / strips;
    const int chunk = rem % chunks;
    const int img = rem / chunks;
    const int y0 = chunk * chunkH;
    const int nout = min(chunkH, H - y0);
    const size_t ibase = (size_t)img * H * W;
    const size_t obase = DS ? (size_t)img * (size_t)(H >> 1) * (W >> 1) : 0;
    const bool edge = (strip == 0) || (strip * 64 + 69 > W);  // wave-uniform
    if (edge)
      sum = strip_run<1, DS, LAST>(P + ibase, T + ibase, H, W, y0, nout,
                                   strip * 64, dsP, dsT, obase,
                                   G0, G1, G2, G3, G4, G5, G6, G7, G8, G9, G10);
    else
      sum = strip_run<0, DS, LAST>(P + ibase, T + ibase, H, W, y0, nout,
                                   strip * 64, dsP, dsT, obase,
                                   G0, G1, G2, G3, G4, G5, G6, G7, G8, G9, G10);
  }
#pragma unroll
  for (int off = 32; off; off >>= 1) sum += __shfl_down(sum, off, 64);
  if (lane == 0) sRed[wid] = sum;
  __syncthreads();
  if (tid == 0)
    partial[blockIdx.x] = (double)(sRed[0] + sRed[1] + sRed[2] + sRed[3]);
}

__global__ void msssim_combine_k(const double* __restrict__ partial,
                                 float* __restrict__ out, const CInfo ci) {
  const int lane = threadIdx.x & 63;
  double lv[5];
#pragma unroll
  for (int L = 0; L < 5; ++L) {
    double s = 0.0;
    for (int i = lane; i < ci.cnt[L]; i += 64) s += partial[ci.base[L] + i];
#pragma unroll
    for (int off = 32; off; off >>= 1) s += __shfl_down(s, off, 64);
    lv[L] = s;
  }
  if (lane == 0) {
    double ms = lv[4] / (48.0 * 32.0 * 32.0);
    ms *= pow(lv[0] / (48.0 * 512.0 * 512.0), (double)0.0448f);
    ms *= pow(lv[1] / (48.0 * 256.0 * 256.0), (double)0.2856f);
    ms *= pow(lv[2] / (48.0 * 128.0 * 128.0), (double)0.3001f);
    ms *= pow(lv[3] / (48.0 * 64.0 * 64.0),  (double)0.2363f);
    out[0] = (float)(1.0 - ms);
  }
}

extern "C" void kernel_launch(void* const* d_in, const int* in_sizes, int n_in,
                              void* d_out, int out_size, void* d_ws, size_t ws_size,
                              hipStream_t stream) {
  const float* pred = (const float*)d_in[0];
  const float* targ = (const float*)d_in[1];
  float* out = (float*)d_out;

  char* ws = (char*)d_ws;
  double* partial = (double*)ws;  // per-block partial sums, 32KB region
  size_t off = 32768;
  auto alloc = [&](size_t elems) {
    float* p = (float*)(ws + off);
    off += elems * sizeof(float);
    return p;
  };
  float* L1p = alloc((size_t)NIMG * 256 * 256);
  float* L1t = alloc((size_t)NIMG * 256 * 256);
  float* L2p = alloc((size_t)NIMG * 128 * 128);
  float* L2t = alloc((size_t)NIMG * 128 * 128);
  float* L3p = alloc((size_t)NIMG * 64 * 64);
  float* L3t = alloc((size_t)NIMG * 64 * 64);
  float* L4p = alloc((size_t)NIMG * 32 * 32);
  float* L4t = alloc((size_t)NIMG * 32 * 32);

  float g[11];
  {
    double gd[11], s = 0.0;
    for (int k = 0; k < 11; ++k) {
      const double c = (double)(k - 5);
      gd[k] = exp(-(c * c) / 4.5);  // 2*sigma^2 = 4.5
      s += gd[k];
    }
    for (int k = 0; k < 11; ++k) g[k] = (float)(gd[k] / s);
  }

  CInfo ci;
  int slotOff = 0;

  auto launchLevel = [&](const float* P, const float* T, int H, int W,
                         int chunkH, float* dP, float* dT, int L, bool last) {
    const int strips = (W + 63) / 64;
    const int chunks = (H + chunkH - 1) / chunkH;
    const int tasks = strips * chunks * NIMG;
    const int blocks = (tasks + 3) / 4;
    ci.base[L] = slotOff;
    ci.cnt[L] = blocks;
    if (last) {
      msssim_level_k<0, 1><<<blocks, 256, 0, stream>>>(
          P, T, H, W, strips, chunks, chunkH, tasks, nullptr, nullptr,
          partial + slotOff, g[0], g[1], g[2], g[3], g[4], g[5], g[6], g[7],
          g[8], g[9], g[10]);
    } else {
      msssim_level_k<1, 0><<<blocks, 256, 0, stream>>>(
          P, T, H, W, strips, chunks, chunkH, tasks, dP, dT,
          partial + slotOff, g[0], g[1], g[2], g[3], g[4], g[5], g[6], g[7],
          g[8], g[9], g[10]);
    }
    slotOff += blocks;
  };

  launchLevel(pred, targ, 512, 512, 64, L1p, L1t, 0, false);
  launchLevel(L1p, L1t, 256, 256, 16, L2p, L2t, 1, false);
  launchLevel(L2p, L2t, 128, 128, 8, L3p, L3t, 2, false);
  launchLevel(L3p, L3t, 64, 64, 8, L4p, L4t, 3, false);
  launchLevel(L4p, L4t, 32, 32, 8, nullptr, nullptr, 4, true);

  msssim_combine_k<<<1, 64, 0, stream>>>(partial, out, ci);
}